// Round 3
// baseline (111.587 us; speedup 1.0000x reference)
//
#include <hip/hip_runtime.h>
#include <stddef.h>

// B=1, H=16, S=4096, D=64, fp32.  out = (Q K^T) V == Q (K^T V)
// Stage 1 (A): P[h][c] = K_chunk^T V_chunk   (64x64 partials, 8x8/thread tiles)
// Stage 2 (R): M[h] = sum_c P[h][c]
// Stage 3 (B): O[h] = Q[h] @ M[h]            (8x8/thread tiles, XOR-swizzled Q in LDS)

#define SLEN 4096
#define DIM  64
#define NH   16
#define CH   32
#define RPC  128   // s-rows per stage-1 chunk (2 tiles of 64)

typedef float f4v __attribute__((ext_vector_type(4)));

// ---------------- Kernel A: partial M = K^T V over a 128-row chunk ----------------
// grid (32,16) x 256 thr. Each WAVE owns the full 64x64 partial over its 32 s-rows
// (8x8 acc per lane: i=lane>>3 rows, j=lane&7 cols); cross-wave LDS reduce at end.
__global__ __launch_bounds__(256) void kvT_partial(const float* __restrict__ K,
                                                   const float* __restrict__ V,
                                                   float* __restrict__ P) {
    const int c = blockIdx.x, h = blockIdx.y, t = threadIdx.x;
    const int wave = t >> 6, lane = t & 63;
    const int i = lane >> 3, j = lane & 7;

    __shared__ float Ks[64][64];   // 16 KB, reused as reduce buffer M0
    __shared__ float Vs[64][64];   // 16 KB, reused as reduce buffer M1

    const f4v* K4 = (const f4v*)(K + ((size_t)h * SLEN + (size_t)c * RPC) * DIM);
    const f4v* V4 = (const f4v*)(V + ((size_t)h * SLEN + (size_t)c * RPC) * DIM);

    float acc[8][8];
    #pragma unroll
    for (int a = 0; a < 8; ++a) {
        #pragma unroll
        for (int b = 0; b < 8; ++b) acc[a][b] = 0.f;
    }

    // staging: 64 rows x 16 f4 = 1024 f4 per array per tile; 4 f4/thread
    f4v kst[4], vst[4];
    #pragma unroll
    for (int u = 0; u < 4; ++u) { kst[u] = K4[u * 256 + t]; vst[u] = V4[u * 256 + t]; }

    for (int tile = 0; tile < 2; ++tile) {
        __syncthreads();                      // protect previous tile's LDS reads
        #pragma unroll
        for (int u = 0; u < 4; ++u) {
            int idx = u * 256 + t, row = idx >> 4, c4 = idx & 15;
            *(f4v*)&Ks[row][c4 * 4] = kst[u];
            *(f4v*)&Vs[row][c4 * 4] = vst[u];
        }
        __syncthreads();
        if (tile == 0) {                      // prefetch tile 1 under compute
            #pragma unroll
            for (int u = 0; u < 4; ++u) {
                kst[u] = K4[1024 + u * 256 + t];
                vst[u] = V4[1024 + u * 256 + t];
            }
        }
        #pragma unroll
        for (int s0 = 0; s0 < 16; ++s0) {
            const int s = wave * 16 + s0;     // waves split the 64 tile rows
            float kf[8], vf[8];
            *(f4v*)&kf[0] = *(const f4v*)&Ks[s][i * 8];       // 8-lane broadcast, 2-way banks
            *(f4v*)&kf[4] = *(const f4v*)&Ks[s][i * 8 + 4];
            *(f4v*)&vf[0] = *(const f4v*)&Vs[s][j * 8];
            *(f4v*)&vf[4] = *(const f4v*)&Vs[s][j * 8 + 4];
            #pragma unroll
            for (int a = 0; a < 8; ++a) {
                #pragma unroll
                for (int b = 0; b < 8; ++b)
                    acc[a][b] = fmaf(kf[a], vf[b], acc[a][b]);
            }
        }
    }

    // ---- cross-wave reduce: (w0+w1) -> Ks, (w2+w3) -> Vs, then Ks+Vs -> P ----
    __syncthreads();
    float* M0 = &Ks[0][0];
    float* M1 = &Vs[0][0];
    if (wave == 0 || wave == 2) {
        float* dst = (wave == 0) ? M0 : M1;
        #pragma unroll
        for (int r = 0; r < 8; ++r) {
            #pragma unroll
            for (int hh = 0; hh < 2; ++hh) {
                f4v x; x[0]=acc[r][hh*4]; x[1]=acc[r][hh*4+1]; x[2]=acc[r][hh*4+2]; x[3]=acc[r][hh*4+3];
                *(f4v*)&dst[(i * 8 + r) * 64 + j * 8 + hh * 4] = x;
            }
        }
    }
    __syncthreads();
    if (wave == 1 || wave == 3) {
        float* dst = (wave == 1) ? M0 : M1;
        #pragma unroll
        for (int r = 0; r < 8; ++r) {
            #pragma unroll
            for (int hh = 0; hh < 2; ++hh) {
                f4v x = *(f4v*)&dst[(i * 8 + r) * 64 + j * 8 + hh * 4];
                x[0]+=acc[r][hh*4]; x[1]+=acc[r][hh*4+1]; x[2]+=acc[r][hh*4+2]; x[3]+=acc[r][hh*4+3];
                *(f4v*)&dst[(i * 8 + r) * 64 + j * 8 + hh * 4] = x;
            }
        }
    }
    __syncthreads();
    float* Pc = P + ((size_t)h * CH + c) * (DIM * DIM);
    #pragma unroll
    for (int u = 0; u < 4; ++u) {
        int idx = u * 256 + t;
        f4v x = ((const f4v*)M0)[idx] + ((const f4v*)M1)[idx];
        ((f4v*)Pc)[idx] = x;
    }
}

// ---------------- Kernel R: M[h] = sum over 32 chunk-partials ----------------
__global__ __launch_bounds__(256) void reduceM(const float* __restrict__ P,
                                               float* __restrict__ M) {
    const int q = blockIdx.x, h = blockIdx.y, t = threadIdx.x;
    const int off = q * 256 + t;
    const f4v* Ph = (const f4v*)(P + (size_t)h * CH * DIM * DIM);
    f4v sum; sum[0]=0.f; sum[1]=0.f; sum[2]=0.f; sum[3]=0.f;
    #pragma unroll
    for (int c = 0; c < CH; ++c) sum += Ph[(size_t)c * (DIM * DIM / 4) + off];
    ((f4v*)(M + (size_t)h * DIM * DIM))[off] = sum;
}

// ---------------- Kernel B: O = Q @ M ----------------
// grid (64,16) x 64 thr (1 wave). Wave computes a full 64x64 output chunk,
// 8x8 per lane. Q stored in LDS with f4-column XOR swizzle (c4^=row>>3) so the
// lane-varying-row qf reads spread across all 8 bank-quads (conflict-free).
__global__ __launch_bounds__(64) void qm_kernel(const float* __restrict__ Q,
                                                const float* __restrict__ Mm,
                                                float* __restrict__ O) {
    const int chunk = blockIdx.x, h = blockIdx.y, lane = threadIdx.x;
    const int i = lane >> 3, j = lane & 7;

    __shared__ float Qs[64][64];
    __shared__ float Ms[64][64];

    const f4v* Q4 = (const f4v*)(Q + ((size_t)h * SLEN + (size_t)chunk * 64) * DIM);
    const f4v* M4 = (const f4v*)(Mm + (size_t)h * DIM * DIM);

    #pragma unroll
    for (int u = 0; u < 16; ++u) {
        int idx = u * 64 + lane, row = idx >> 4, c4 = idx & 15;
        int c4s = c4 ^ (row >> 3);              // XOR swizzle
        *(f4v*)&Qs[row][c4s * 4] = Q4[idx];
        *(f4v*)&Ms[row][c4 * 4]  = M4[idx];
    }
    __syncthreads();

    float acc[8][8];
    #pragma unroll
    for (int a = 0; a < 8; ++a) {
        #pragma unroll
        for (int b = 0; b < 8; ++b) acc[a][b] = 0.f;
    }

    #pragma unroll
    for (int d0 = 0; d0 < DIM; d0 += 4) {
        const int c4q = d0 >> 2;
        float qf[8][4];
        #pragma unroll
        for (int r = 0; r < 8; ++r)             // row = i*8+r -> stored col = c4q ^ i
            *(f4v*)&qf[r][0] = *(const f4v*)&Qs[i * 8 + r][(c4q ^ i) * 4];
        float mf[4][8];
        #pragma unroll
        for (int cc = 0; cc < 4; ++cc) {
            *(f4v*)&mf[cc][0] = *(const f4v*)&Ms[d0 + cc][j * 8];
            *(f4v*)&mf[cc][4] = *(const f4v*)&Ms[d0 + cc][j * 8 + 4];
        }
        #pragma unroll
        for (int r = 0; r < 8; ++r) {
            #pragma unroll
            for (int cc = 0; cc < 4; ++cc) {
                #pragma unroll
                for (int b = 0; b < 8; ++b)
                    acc[r][b] = fmaf(qf[r][cc], mf[cc][b], acc[r][b]);
            }
        }
    }

    float* Orow = O + ((size_t)h * SLEN + (size_t)chunk * 64) * DIM;
    #pragma unroll
    for (int r = 0; r < 8; ++r) {
        #pragma unroll
        for (int hh = 0; hh < 2; ++hh) {
            f4v x; x[0]=acc[r][hh*4]; x[1]=acc[r][hh*4+1]; x[2]=acc[r][hh*4+2]; x[3]=acc[r][hh*4+3];
            *(f4v*)&Orow[(i * 8 + r) * DIM + j * 8 + hh * 4] = x;
        }
    }
}

extern "C" void kernel_launch(void* const* d_in, const int* in_sizes, int n_in,
                              void* d_out, int out_size, void* d_ws, size_t ws_size,
                              hipStream_t stream) {
    const float* q = (const float*)d_in[0];
    const float* k = (const float*)d_in[1];
    const float* v = (const float*)d_in[2];
    float* out = (float*)d_out;
    float* P = (float*)d_ws;                                  // 8 MiB
    float* M = P + (size_t)NH * CH * DIM * DIM;               // 256 KiB

    kvT_partial<<<dim3(CH, NH), 256, 0, stream>>>(k, v, P);
    reduceM<<<dim3(4, NH), 256, 0, stream>>>(P, M);
    qm_kernel<<<dim3(SLEN / 64, NH), 64, 0, stream>>>(q, M, out);
}